// Round 12
// baseline (2017.559 us; speedup 1.0000x reference)
//
#include <hip/hip_runtime.h>
#include <hip/hip_cooperative_groups.h>
namespace cg = cooperative_groups;

#define H 128
#define SHIFT 9             // nodes per coarse bucket = 512
#define BN 512
#define MAXNB 256
#define CHUNK 4096          // edges per scatter block-iteration
#define CAP 16384           // slack capacity per bucket
#define CSTRIDE (H * 16 + 4)   // fallback GEMM LDS layout

// ===================================================================================
// Shared device helpers
// ===================================================================================

__device__ __forceinline__ float4 gather_row_sum(const float4* __restrict__ hs4,
                                                 const int* __restrict__ csr,
                                                 int node, int e0, int e1, int half, int l) {
    float4 acc[8];
    #pragma unroll
    for (int u = 0; u < 8; ++u) acc[u] = make_float4(0.f, 0.f, 0.f, 0.f);
    if (half == 0) acc[0] = hs4[(size_t)node * 32 + l];   // self loop
    int q = e0;
    for (; q + 15 < e1; q += 16) {
        int idx[8];
        #pragma unroll
        for (int u = 0; u < 8; ++u) idx[u] = csr[q + 2 * u + half];
        #pragma unroll
        for (int u = 0; u < 8; ++u) {
            float4 v = hs4[(size_t)idx[u] * 32 + l];
            acc[u].x += v.x; acc[u].y += v.y; acc[u].z += v.z; acc[u].w += v.w;
        }
    }
    for (; q + 7 < e1; q += 8) {
        int idx[4];
        #pragma unroll
        for (int u = 0; u < 4; ++u) idx[u] = csr[q + 2 * u + half];
        #pragma unroll
        for (int u = 0; u < 4; ++u) {
            float4 v = hs4[(size_t)idx[u] * 32 + l];
            acc[u].x += v.x; acc[u].y += v.y; acc[u].z += v.z; acc[u].w += v.w;
        }
    }
    for (; q < e1; q += 2) {
        int off = q + half;
        if (off < e1) {
            float4 v = hs4[(size_t)csr[off] * 32 + l];
            acc[0].x += v.x; acc[0].y += v.y; acc[0].z += v.z; acc[0].w += v.w;
        }
    }
    float4 sum;
    sum.x = ((acc[0].x + acc[1].x) + (acc[2].x + acc[3].x)) + ((acc[4].x + acc[5].x) + (acc[6].x + acc[7].x));
    sum.y = ((acc[0].y + acc[1].y) + (acc[2].y + acc[3].y)) + ((acc[4].y + acc[5].y) + (acc[6].y + acc[7].y));
    sum.z = ((acc[0].z + acc[1].z) + (acc[2].z + acc[3].z)) + ((acc[4].z + acc[5].z) + (acc[6].z + acc[7].z));
    sum.w = ((acc[0].w + acc[1].w) + (acc[2].w + acc[3].w)) + ((acc[4].w + acc[5].w) + (acc[6].w + acc[7].w));
    sum.x += __shfl_xor(sum.x, 32);
    sum.y += __shfl_xor(sum.y, 32);
    sum.z += __shfl_xor(sum.z, 32);
    sum.w += __shfl_xor(sum.w, 32);
    return sum;
}

__device__ __forceinline__ void stage_WT(const float* __restrict__ W, float* __restrict__ WT) {
    for (int idx = threadIdx.x; idx < H * H / 4; idx += 256) {
        float4 v = ((const float4*)W)[idx];
        int k  = idx >> 5;
        int c4 = idx & 31;
        int cc = c4 >> 2;
        int j  = (c4 & 3) * 4;
        *(float4*)(WT + cc * CSTRIDE + k * 16 + j) = v;
    }
}

// ===================================================================================
// Cooperative mega-kernel
// ===================================================================================

struct SmemSc { unsigned stage[CHUNK]; unsigned char stb[CHUNK];
                int hist[MAXNB], basel[MAXNB], cur[MAXNB], gbase[MAXNB]; int total; };
struct SmemBc { int hist[BN]; int cur[BN]; int ps[256]; };
union SmemU { SmemSc sc; SmemBc bc; };

__global__ __launch_bounds__(256, 4) void mega_k(
    const float* __restrict__ x, const int* __restrict__ src, const int* __restrict__ dst,
    const int* __restrict__ batch,
    const float* __restrict__ W1, const float* __restrict__ b1,
    const float* __restrict__ W2, const float* __restrict__ b2,
    const float* __restrict__ W3, const float* __restrict__ b3,
    const float* __restrict__ Wl1, const float* __restrict__ bl1,
    const float* __restrict__ Wl2, const float* __restrict__ bl2,
    const float* __restrict__ Wl3, const float* __restrict__ bl3,
    int* gcur, int* offs, int* eend, int* csr,
    float* dinv, float* sbuf, float2* td,
    float* A, float* B, float* P, float* out,
    int N, int E, int G, int NB, int nChunks, int nTiles)
{
    __shared__ SmemU sm;
    cg::grid_group grid = cg::this_grid();
    const int tid = threadIdx.x;
    const int gsize = gridDim.x * 256;
    const int gtid = blockIdx.x * 256 + tid;
    unsigned* pairbuf = (unsigned*)B;

    // ---- P-1: zero bucket cursors ----
    for (int i = gtid; i < MAXNB; i += gsize) gcur[i] = 0;
    __threadfence(); grid.sync();

    // ---- P0: scatter edges into slack buckets ----
    for (int c = blockIdx.x; c < nChunks; c += gridDim.x) {
        int base = c * CHUNK;
        int mysrc[16], mydst[16];
        #pragma unroll
        for (int i = 0; i < 16; ++i) {
            int e = base + i * 256 + tid;
            if (e < E) { mysrc[i] = src[e]; mydst[i] = dst[e]; } else mydst[i] = -1;
        }
        sm.sc.hist[tid] = 0;
        __syncthreads();
        #pragma unroll
        for (int i = 0; i < 16; ++i)
            if (mydst[i] >= 0) atomicAdd(&sm.sc.hist[mydst[i] >> SHIFT], 1);
        __syncthreads();
        if (tid == 0) {
            int run = 0;
            for (int b = 0; b < NB; ++b) { sm.sc.basel[b] = run; run += sm.sc.hist[b]; }
            sm.sc.total = run;
        }
        __syncthreads();
        if (tid < NB) {
            sm.sc.cur[tid] = sm.sc.basel[tid];
            if (sm.sc.hist[tid] > 0)
                sm.sc.gbase[tid] = tid * CAP + atomicAdd(&gcur[tid], sm.sc.hist[tid]);
        }
        __syncthreads();
        #pragma unroll
        for (int i = 0; i < 16; ++i)
            if (mydst[i] >= 0) {
                int b = mydst[i] >> SHIFT;
                int slot = atomicAdd(&sm.sc.cur[b], 1);
                sm.sc.stage[slot] = ((unsigned)(mydst[i] & (BN - 1)) << 17) | (unsigned)mysrc[i];
                sm.sc.stb[slot] = (unsigned char)b;
            }
        __syncthreads();
        int total = sm.sc.total;
        for (int s = tid; s < total; s += 256) {
            int b = sm.sc.stb[s];
            pairbuf[sm.sc.gbase[b] + (s - sm.sc.basel[b])] = sm.sc.stage[s];
        }
        __syncthreads();
    }
    __threadfence(); grid.sync();

    // ---- P1: per-bucket CSR build (+dinv, +s fused) ----
    for (int b = blockIdx.x; b < NB; b += gridDim.x) {
        int node0 = b << SHIFT;
        int e0 = b * CAP, e1 = e0 + gcur[b];
        sm.bc.hist[tid] = 0; sm.bc.hist[tid + 256] = 0;
        __syncthreads();
        for (int p = e0 + tid; p < e1; p += 256)
            atomicAdd(&sm.bc.hist[pairbuf[p] >> 17], 1);
        __syncthreads();
        int v0 = sm.bc.hist[2 * tid], v1 = sm.bc.hist[2 * tid + 1];
        int pairsum = v0 + v1;
        sm.bc.ps[tid] = pairsum;
        __syncthreads();
        for (int off = 1; off < 256; off <<= 1) {
            int t = (tid >= off) ? sm.bc.ps[tid - off] : 0;
            __syncthreads();
            sm.bc.ps[tid] += t;
            __syncthreads();
        }
        int g0 = e0 + sm.bc.ps[tid] - pairsum;
        int n0 = node0 + 2 * tid, n1 = n0 + 1;
        if (n0 < N) {
            float d = rsqrtf((float)(v0 + 1));
            offs[n0] = g0; eend[n0] = g0 + v0; dinv[n0] = d; sbuf[n0] = x[n0] * d;
        }
        if (n1 < N) {
            float d = rsqrtf((float)(v1 + 1));
            offs[n1] = g0 + v0; eend[n1] = g0 + v0 + v1; dinv[n1] = d; sbuf[n1] = x[n1] * d;
        }
        sm.bc.cur[2 * tid] = g0; sm.bc.cur[2 * tid + 1] = g0 + v0;
        __syncthreads();
        for (int p = e0 + tid; p < e1; p += 256) {
            unsigned v = pairbuf[p];
            int pos = atomicAdd(&sm.bc.cur[v >> 17], 1);
            csr[pos] = (int)(v & 0x1FFFFu);
        }
        __syncthreads();
    }
    __threadfence(); grid.sync();

    // ---- P2: layer-1 scalar aggregation ----
    for (int i = gtid; i < N; i += gsize) {
        float sum = sbuf[i];
        int e0 = offs[i], e1 = eend[i];
        float a0 = 0.f, a1 = 0.f, a2 = 0.f, a3 = 0.f;
        int p = e0;
        for (; p + 4 <= e1; p += 4) {
            a0 += sbuf[csr[p]]; a1 += sbuf[csr[p + 1]];
            a2 += sbuf[csr[p + 2]]; a3 += sbuf[csr[p + 3]];
        }
        for (; p < e1; ++p) sum += sbuf[csr[p]];
        sum += (a0 + a1) + (a2 + a3);
        float d = dinv[i];
        td[i] = make_float2(sum * d, d);
    }
    __threadfence(); grid.sync();

    // ---- P3: layer-2 scalar-gather aggregation -> U2 in A ----
    {
        int lane = tid & 63;
        float wa = W1[lane], wb = W1[lane + 64];
        float ba = b1[lane], bb = b1[lane + 64];
        int wave0 = blockIdx.x * 4 + (tid >> 6);
        for (int node = wave0; node < N; node += gridDim.x * 4) {
            float2 self = td[node];
            float sa = fmaxf(fmaf(self.x, wa, ba), 0.f) * self.y;
            float sb = fmaxf(fmaf(self.x, wb, bb), 0.f) * self.y;
            int e0 = offs[node], e1 = eend[node];
            int p = e0;
            for (; p + 8 <= e1; p += 8) {
                float2 v[8];
                #pragma unroll
                for (int u = 0; u < 8; ++u) v[u] = td[csr[p + u]];
                #pragma unroll
                for (int u = 0; u < 8; ++u) {
                    sa = fmaf(fmaxf(fmaf(v[u].x, wa, ba), 0.f), v[u].y, sa);
                    sb = fmaf(fmaxf(fmaf(v[u].x, wb, bb), 0.f), v[u].y, sb);
                }
            }
            for (; p < e1; ++p) {
                float2 v = td[csr[p]];
                sa = fmaf(fmaxf(fmaf(v.x, wa, ba), 0.f), v.y, sa);
                sb = fmaf(fmaxf(fmaf(v.x, wb, bb), 0.f), v.y, sb);
            }
            float d = self.y;
            A[(size_t)node * H + lane]      = sa * d;
            A[(size_t)node * H + lane + 64] = sb * d;
        }
    }
    __threadfence(); grid.sync();

    // ---- P4: layer-2 GEMM: B = Z2 = dinv * relu(A@W2 + b2) ----
    {
        const int cc = tid & 7, rg = tid >> 3, c0 = cc * 16;
        for (int t = blockIdx.x; t < nTiles; t += gridDim.x) {
            const int row0 = t * 128 + rg * 4;
            const float* p[4];
            #pragma unroll
            for (int r = 0; r < 4; ++r) {
                int rr = row0 + r; if (rr > N - 1) rr = N - 1;
                p[r] = A + (size_t)rr * H;
            }
            float acc[4][16];
            #pragma unroll
            for (int r = 0; r < 4; ++r)
                #pragma unroll
                for (int j = 0; j < 16; ++j) acc[r][j] = 0.f;
            for (int k4 = 0; k4 < H / 4; ++k4) {
                float4 a[4];
                #pragma unroll
                for (int r = 0; r < 4; ++r) a[r] = *(const float4*)(p[r] + k4 * 4);
                #pragma unroll
                for (int kk = 0; kk < 4; ++kk) {
                    const float* wrow = W2 + (size_t)(k4 * 4 + kk) * H + c0;
                    float w[16];
                    *(float4*)(w + 0)  = *(const float4*)(wrow + 0);
                    *(float4*)(w + 4)  = *(const float4*)(wrow + 4);
                    *(float4*)(w + 8)  = *(const float4*)(wrow + 8);
                    *(float4*)(w + 12) = *(const float4*)(wrow + 12);
                    float av[4];
                    #pragma unroll
                    for (int r = 0; r < 4; ++r) av[r] = ((const float*)&a[r])[kk];
                    #pragma unroll
                    for (int r = 0; r < 4; ++r)
                        #pragma unroll
                        for (int j = 0; j < 16; ++j)
                            acc[r][j] = fmaf(av[r], w[j], acc[r][j]);
                }
            }
            #pragma unroll
            for (int r = 0; r < 4; ++r) {
                int row = row0 + r;
                if (row < N) {
                    float sc = dinv[row];
                    float* orow = B + (size_t)row * H + c0;
                    #pragma unroll
                    for (int j4 = 0; j4 < 4; ++j4) {
                        float4 o;
                        o.x = fmaxf(acc[r][j4 * 4 + 0] + b2[c0 + j4 * 4 + 0], 0.f) * sc;
                        o.y = fmaxf(acc[r][j4 * 4 + 1] + b2[c0 + j4 * 4 + 1], 0.f) * sc;
                        o.z = fmaxf(acc[r][j4 * 4 + 2] + b2[c0 + j4 * 4 + 2], 0.f) * sc;
                        o.w = fmaxf(acc[r][j4 * 4 + 3] + b2[c0 + j4 * 4 + 3], 0.f) * sc;
                        *(float4*)(orow + j4 * 4) = o;
                    }
                }
            }
        }
    }
    __threadfence(); grid.sync();

    // ---- P5: layer-3 row-gather aggregation: A = U3 ----
    {
        int lane = tid & 63;
        int half = lane >> 5, l = lane & 31;
        int wave0 = blockIdx.x * 4 + (tid >> 6);
        const float4* Z4 = (const float4*)B;
        for (int node = wave0; node < N; node += gridDim.x * 4) {
            float4 sum = gather_row_sum(Z4, csr, node, offs[node], eend[node], half, l);
            if (half == 0) {
                float d = dinv[node];
                float4 o;
                o.x = sum.x * d; o.y = sum.y * d; o.z = sum.z * d; o.w = sum.w * d;
                ((float4*)A)[(size_t)node * 32 + l] = o;
            }
        }
    }
    __threadfence(); grid.sync();

    // ---- P6: layer-3 GEMM: B = h3 = relu(A@W3 + b3) ----
    {
        const int cc = tid & 7, rg = tid >> 3, c0 = cc * 16;
        for (int t = blockIdx.x; t < nTiles; t += gridDim.x) {
            const int row0 = t * 128 + rg * 4;
            const float* p[4];
            #pragma unroll
            for (int r = 0; r < 4; ++r) {
                int rr = row0 + r; if (rr > N - 1) rr = N - 1;
                p[r] = A + (size_t)rr * H;
            }
            float acc[4][16];
            #pragma unroll
            for (int r = 0; r < 4; ++r)
                #pragma unroll
                for (int j = 0; j < 16; ++j) acc[r][j] = 0.f;
            for (int k4 = 0; k4 < H / 4; ++k4) {
                float4 a[4];
                #pragma unroll
                for (int r = 0; r < 4; ++r) a[r] = *(const float4*)(p[r] + k4 * 4);
                #pragma unroll
                for (int kk = 0; kk < 4; ++kk) {
                    const float* wrow = W3 + (size_t)(k4 * 4 + kk) * H + c0;
                    float w[16];
                    *(float4*)(w + 0)  = *(const float4*)(wrow + 0);
                    *(float4*)(w + 4)  = *(const float4*)(wrow + 4);
                    *(float4*)(w + 8)  = *(const float4*)(wrow + 8);
                    *(float4*)(w + 12) = *(const float4*)(wrow + 12);
                    float av[4];
                    #pragma unroll
                    for (int r = 0; r < 4; ++r) av[r] = ((const float*)&a[r])[kk];
                    #pragma unroll
                    for (int r = 0; r < 4; ++r)
                        #pragma unroll
                        for (int j = 0; j < 16; ++j)
                            acc[r][j] = fmaf(av[r], w[j], acc[r][j]);
                }
            }
            #pragma unroll
            for (int r = 0; r < 4; ++r) {
                int row = row0 + r;
                if (row < N) {
                    float* orow = B + (size_t)row * H + c0;
                    #pragma unroll
                    for (int j4 = 0; j4 < 4; ++j4) {
                        float4 o;
                        o.x = fmaxf(acc[r][j4 * 4 + 0] + b3[c0 + j4 * 4 + 0], 0.f);
                        o.y = fmaxf(acc[r][j4 * 4 + 1] + b3[c0 + j4 * 4 + 1], 0.f);
                        o.z = fmaxf(acc[r][j4 * 4 + 2] + b3[c0 + j4 * 4 + 2], 0.f);
                        o.w = fmaxf(acc[r][j4 * 4 + 3] + b3[c0 + j4 * 4 + 3], 0.f);
                        *(float4*)(orow + j4 * 4) = o;
                    }
                }
            }
        }
    }
    __threadfence(); grid.sync();

    // ---- P7: mean pool ----
    {
        int f = tid & 127;
        for (int g = blockIdx.x * 2 + (tid >> 7); g < G; g += gridDim.x * 2) {
            int lo = 0, hi = N;
            while (lo < hi) { int m = (lo + hi) >> 1; if (batch[m] < g) lo = m + 1; else hi = m; }
            int s0 = lo;
            hi = N;
            while (lo < hi) { int m = (lo + hi) >> 1; if (batch[m] < g + 1) lo = m + 1; else hi = m; }
            int s1 = lo;
            float a0 = 0.f, a1 = 0.f, a2 = 0.f, a3 = 0.f;
            int i = s0;
            for (; i + 4 <= s1; i += 4) {
                a0 += B[(size_t)i * H + f];
                a1 += B[(size_t)(i + 1) * H + f];
                a2 += B[(size_t)(i + 2) * H + f];
                a3 += B[(size_t)(i + 3) * H + f];
            }
            for (; i < s1; ++i) a0 += B[(size_t)i * H + f];
            float sum = (a0 + a1) + (a2 + a3);
            float c = (float)(s1 - s0); if (c < 1.f) c = 1.f;
            P[(size_t)g * H + f] = sum / c;
        }
    }
    __threadfence(); grid.sync();

    // ---- P8: head layer 1 -> A ----
    {
        const int cc = tid & 7, rg = tid >> 3, c0 = cc * 16;
        const float4* P4 = (const float4*)P;
        for (int t = blockIdx.x; t < (G + 127) / 128; t += gridDim.x) {
            int g0 = t * 128;
            float acc[4][16];
            #pragma unroll
            for (int r = 0; r < 4; ++r)
                #pragma unroll
                for (int j = 0; j < 16; ++j) acc[r][j] = 0.f;
            for (int k4 = 0; k4 < H / 4; ++k4) {
                float4 a[4];
                #pragma unroll
                for (int r = 0; r < 4; ++r) a[r] = P4[(size_t)(g0 + rg * 4 + r) * 32 + k4];
                #pragma unroll
                for (int kk = 0; kk < 4; ++kk) {
                    const float* wrow = Wl1 + (size_t)(k4 * 4 + kk) * H + c0;
                    float w[16];
                    *(float4*)(w + 0)  = *(const float4*)(wrow + 0);
                    *(float4*)(w + 4)  = *(const float4*)(wrow + 4);
                    *(float4*)(w + 8)  = *(const float4*)(wrow + 8);
                    *(float4*)(w + 12) = *(const float4*)(wrow + 12);
                    float av[4];
                    #pragma unroll
                    for (int r = 0; r < 4; ++r) av[r] = ((const float*)&a[r])[kk];
                    #pragma unroll
                    for (int r = 0; r < 4; ++r)
                        #pragma unroll
                        for (int j = 0; j < 16; ++j)
                            acc[r][j] = fmaf(av[r], w[j], acc[r][j]);
                }
            }
            #pragma unroll
            for (int r = 0; r < 4; ++r) {
                float* orow = A + (size_t)(g0 + rg * 4 + r) * H + c0;
                #pragma unroll
                for (int j4 = 0; j4 < 4; ++j4) {
                    float4 o;
                    o.x = fmaxf(acc[r][j4 * 4 + 0] + bl1[c0 + j4 * 4 + 0], 0.f);
                    o.y = fmaxf(acc[r][j4 * 4 + 1] + bl1[c0 + j4 * 4 + 1], 0.f);
                    o.z = fmaxf(acc[r][j4 * 4 + 2] + bl1[c0 + j4 * 4 + 2], 0.f);
                    o.w = fmaxf(acc[r][j4 * 4 + 3] + bl1[c0 + j4 * 4 + 3], 0.f);
                    *(float4*)(orow + j4 * 4) = o;
                }
            }
        }
    }
    __threadfence(); grid.sync();

    // ---- P9: head layer 2 + output dot ----
    {
        const int cc = tid & 7, rg = tid >> 3, c0 = cc * 16;
        const float4* Q4 = (const float4*)A;
        for (int t = blockIdx.x; t < (G + 127) / 128; t += gridDim.x) {
            int g0 = t * 128;
            float acc[4][16];
            #pragma unroll
            for (int r = 0; r < 4; ++r)
                #pragma unroll
                for (int j = 0; j < 16; ++j) acc[r][j] = 0.f;
            for (int k4 = 0; k4 < H / 4; ++k4) {
                float4 a[4];
                #pragma unroll
                for (int r = 0; r < 4; ++r) a[r] = Q4[(size_t)(g0 + rg * 4 + r) * 32 + k4];
                #pragma unroll
                for (int kk = 0; kk < 4; ++kk) {
                    const float* wrow = Wl2 + (size_t)(k4 * 4 + kk) * H + c0;
                    float w[16];
                    *(float4*)(w + 0)  = *(const float4*)(wrow + 0);
                    *(float4*)(w + 4)  = *(const float4*)(wrow + 4);
                    *(float4*)(w + 8)  = *(const float4*)(wrow + 8);
                    *(float4*)(w + 12) = *(const float4*)(wrow + 12);
                    float av[4];
                    #pragma unroll
                    for (int r = 0; r < 4; ++r) av[r] = ((const float*)&a[r])[kk];
                    #pragma unroll
                    for (int r = 0; r < 4; ++r)
                        #pragma unroll
                        for (int j = 0; j < 16; ++j)
                            acc[r][j] = fmaf(av[r], w[j], acc[r][j]);
                }
            }
            float part[4];
            #pragma unroll
            for (int r = 0; r < 4; ++r) {
                float s = 0.f;
                #pragma unroll
                for (int j = 0; j < 16; ++j)
                    s += fmaxf(acc[r][j] + bl2[c0 + j], 0.f) * Wl3[c0 + j];
                part[r] = s;
            }
            #pragma unroll
            for (int off = 1; off < 8; off <<= 1)
                #pragma unroll
                for (int r = 0; r < 4; ++r) part[r] += __shfl_xor(part[r], off);
            if (cc == 0) {
                float bb = bl3[0];
                #pragma unroll
                for (int r = 0; r < 4; ++r) out[g0 + rg * 4 + r] = part[r] + bb;
            }
        }
    }
}

// ===================================================================================
// Fallback path: R10 multi-kernel pipeline (known-good, 505 us)
// ===================================================================================

__global__ __launch_bounds__(256) void scatter_pairs_k(const int* __restrict__ src,
                                                       const int* __restrict__ dst,
                                                       int* __restrict__ gcur,
                                                       unsigned* __restrict__ pairbuf,
                                                       int E, int NBv) {
    __shared__ unsigned stage[CHUNK];
    __shared__ unsigned char stb[CHUNK];
    __shared__ int hist[MAXNB], basel[MAXNB], cur[MAXNB], gbase[MAXNB];
    __shared__ int total;
    int tid = threadIdx.x;
    int base = blockIdx.x * CHUNK;

    int mysrc[16], mydst[16];
    #pragma unroll
    for (int i = 0; i < 16; ++i) {
        int e = base + i * 256 + tid;
        if (e < E) { mysrc[i] = src[e]; mydst[i] = dst[e]; } else mydst[i] = -1;
    }
    hist[tid] = 0;
    __syncthreads();
    #pragma unroll
    for (int i = 0; i < 16; ++i)
        if (mydst[i] >= 0) atomicAdd(&hist[mydst[i] >> SHIFT], 1);
    __syncthreads();
    if (tid == 0) {
        int run = 0;
        for (int b = 0; b < NBv; ++b) { basel[b] = run; run += hist[b]; }
        total = run;
    }
    __syncthreads();
    if (tid < NBv) {
        cur[tid] = basel[tid];
        if (hist[tid] > 0) gbase[tid] = tid * CAP + atomicAdd(&gcur[tid], hist[tid]);
    }
    __syncthreads();
    #pragma unroll
    for (int i = 0; i < 16; ++i)
        if (mydst[i] >= 0) {
            int b = mydst[i] >> SHIFT;
            int slot = atomicAdd(&cur[b], 1);
            stage[slot] = ((unsigned)(mydst[i] & (BN - 1)) << 17) | (unsigned)mysrc[i];
            stb[slot] = (unsigned char)b;
        }
    __syncthreads();
    for (int s = tid; s < total; s += 256) {
        int b = stb[s];
        pairbuf[gbase[b] + (s - basel[b])] = stage[s];
    }
}

__global__ __launch_bounds__(512) void build_csr_k(const unsigned* __restrict__ pairbuf,
                                                   const int* __restrict__ gcur,
                                                   const float* __restrict__ x,
                                                   int* __restrict__ offs, int* __restrict__ eend,
                                                   float* __restrict__ dinv, float* __restrict__ s,
                                                   int* __restrict__ csr, int N) {
    __shared__ int hist[BN];
    __shared__ int cur[BN];
    __shared__ int ps[BN];
    int b = blockIdx.x, tid = threadIdx.x;
    int node0 = b << SHIFT;
    int e0 = b * CAP, e1 = e0 + gcur[b];
    hist[tid] = 0;
    __syncthreads();
    for (int p = e0 + tid; p < e1; p += 512)
        atomicAdd(&hist[pairbuf[p] >> 17], 1);
    __syncthreads();
    int v0 = hist[tid];
    ps[tid] = v0;
    __syncthreads();
    for (int off = 1; off < BN; off <<= 1) {
        int t = (tid >= off) ? ps[tid - off] : 0;
        __syncthreads();
        ps[tid] += t;
        __syncthreads();
    }
    int g0 = e0 + ps[tid] - v0;
    int n0 = node0 + tid;
    if (n0 < N) {
        float d = rsqrtf((float)(v0 + 1));
        offs[n0] = g0; eend[n0] = g0 + v0; dinv[n0] = d; s[n0] = x[n0] * d;
    }
    cur[tid] = g0;
    __syncthreads();
    for (int p = e0 + tid; p < e1; p += 512) {
        unsigned v = pairbuf[p];
        int pos = atomicAdd(&cur[v >> 17], 1);
        csr[pos] = (int)(v & 0x1FFFFu);
    }
}

__global__ void agg1_k(const float* __restrict__ s, const int* __restrict__ offs,
                       const int* __restrict__ eend, const int* __restrict__ csr,
                       const float* __restrict__ dinv, float2* __restrict__ td, int n) {
    int i = blockIdx.x * blockDim.x + threadIdx.x;
    if (i >= n) return;
    float sum = s[i];
    int e0 = offs[i], e1 = eend[i];
    float a0 = 0.f, a1 = 0.f, a2 = 0.f, a3 = 0.f;
    int p = e0;
    for (; p + 4 <= e1; p += 4) {
        a0 += s[csr[p]]; a1 += s[csr[p + 1]]; a2 += s[csr[p + 2]]; a3 += s[csr[p + 3]];
    }
    for (; p < e1; ++p) sum += s[csr[p]];
    sum += (a0 + a1) + (a2 + a3);
    float d = dinv[i];
    td[i] = make_float2(sum * d, d);
}

__global__ __launch_bounds__(256) void l2_agg_k(const float2* __restrict__ td,
                                                const int* __restrict__ offs,
                                                const int* __restrict__ eend,
                                                const int* __restrict__ csr,
                                                const float* __restrict__ w1,
                                                const float* __restrict__ b1,
                                                float* __restrict__ U, int n) {
    int node = blockIdx.x * 4 + (threadIdx.x >> 6);
    int lane = threadIdx.x & 63;
    if (node >= n) return;
    float wa = w1[lane],      wb = w1[lane + 64];
    float ba = b1[lane],      bb = b1[lane + 64];
    float2 self = td[node];
    float sa = fmaxf(fmaf(self.x, wa, ba), 0.f) * self.y;
    float sb = fmaxf(fmaf(self.x, wb, bb), 0.f) * self.y;
    int e0 = offs[node], e1 = eend[node];
    int p = e0;
    for (; p + 8 <= e1; p += 8) {
        float2 v[8];
        #pragma unroll
        for (int u = 0; u < 8; ++u) v[u] = td[csr[p + u]];
        #pragma unroll
        for (int u = 0; u < 8; ++u) {
            sa = fmaf(fmaxf(fmaf(v[u].x, wa, ba), 0.f), v[u].y, sa);
            sb = fmaf(fmaxf(fmaf(v[u].x, wb, bb), 0.f), v[u].y, sb);
        }
    }
    for (; p < e1; ++p) {
        float2 v = td[csr[p]];
        sa = fmaf(fmaxf(fmaf(v.x, wa, ba), 0.f), v.y, sa);
        sb = fmaf(fmaxf(fmaf(v.x, wb, bb), 0.f), v.y, sb);
    }
    float d = self.y;
    U[(size_t)node * H + lane]      = sa * d;
    U[(size_t)node * H + lane + 64] = sb * d;
}

__global__ __launch_bounds__(256) void gemm_post_k(const float* __restrict__ in, const float* __restrict__ W,
                                                   const float* __restrict__ bias, const float* __restrict__ pscale,
                                                   float* __restrict__ out, int n) {
    __shared__ float WT[8 * CSTRIDE];
    stage_WT(W, WT);
    __syncthreads();
    const int cc = threadIdx.x & 7;
    const int rg = threadIdx.x >> 3;
    const int c0 = cc * 16;
    const int row0 = blockIdx.x * 128 + rg * 4;
    const float* wt = WT + cc * CSTRIDE;

    const float* p[4];
    #pragma unroll
    for (int r = 0; r < 4; ++r) {
        int rr = row0 + r; if (rr > n - 1) rr = n - 1;
        p[r] = in + (size_t)rr * H;
    }
    float acc[4][16];
    #pragma unroll
    for (int r = 0; r < 4; ++r)
        #pragma unroll
        for (int j = 0; j < 16; ++j) acc[r][j] = 0.f;
    for (int k4 = 0; k4 < H / 4; ++k4) {
        float4 a[4];
        #pragma unroll
        for (int r = 0; r < 4; ++r) a[r] = *(const float4*)(p[r] + k4 * 4);
        #pragma unroll
        for (int kk = 0; kk < 4; ++kk) {
            const float* wb = wt + (k4 * 4 + kk) * 16;
            float w[16];
            *(float4*)(w + 0)  = *(const float4*)(wb + 0);
            *(float4*)(w + 4)  = *(const float4*)(wb + 4);
            *(float4*)(w + 8)  = *(const float4*)(wb + 8);
            *(float4*)(w + 12) = *(const float4*)(wb + 12);
            float av[4];
            #pragma unroll
            for (int r = 0; r < 4; ++r) av[r] = ((const float*)&a[r])[kk];
            #pragma unroll
            for (int r = 0; r < 4; ++r)
                #pragma unroll
                for (int j = 0; j < 16; ++j)
                    acc[r][j] = fmaf(av[r], w[j], acc[r][j]);
        }
    }
    #pragma unroll
    for (int r = 0; r < 4; ++r) {
        int row = row0 + r;
        if (row < n) {
            float sc = pscale[row];
            float* orow = out + (size_t)row * H + c0;
            #pragma unroll
            for (int j4 = 0; j4 < 4; ++j4) {
                float4 o;
                o.x = fmaxf(acc[r][j4 * 4 + 0] + bias[c0 + j4 * 4 + 0], 0.f) * sc;
                o.y = fmaxf(acc[r][j4 * 4 + 1] + bias[c0 + j4 * 4 + 1], 0.f) * sc;
                o.z = fmaxf(acc[r][j4 * 4 + 2] + bias[c0 + j4 * 4 + 2], 0.f) * sc;
                o.w = fmaxf(acc[r][j4 * 4 + 3] + bias[c0 + j4 * 4 + 3], 0.f) * sc;
                *(float4*)(orow + j4 * 4) = o;
            }
        }
    }
}

__global__ __launch_bounds__(256) void agg3_k(const float* __restrict__ Z, const int* __restrict__ offs,
                                              const int* __restrict__ eend, const int* __restrict__ csr,
                                              const float* __restrict__ dinv,
                                              float* __restrict__ U, int n) {
    int node = blockIdx.x * 4 + (threadIdx.x >> 6);
    int lane = threadIdx.x & 63;
    int half = lane >> 5;
    int l = lane & 31;
    if (node >= n) return;
    const float4* Z4 = (const float4*)Z;
    float4 sum = gather_row_sum(Z4, csr, node, offs[node], eend[node], half, l);
    if (half == 0) {
        float d = dinv[node];
        float4 o;
        o.x = sum.x * d; o.y = sum.y * d; o.z = sum.z * d; o.w = sum.w * d;
        ((float4*)U)[(size_t)node * 32 + l] = o;
    }
}

__global__ __launch_bounds__(256) void gemm_k(const float* __restrict__ in, const float* __restrict__ W,
                                              const float* __restrict__ bias,
                                              float* __restrict__ out, int n) {
    __shared__ float WT[8 * CSTRIDE];
    stage_WT(W, WT);
    __syncthreads();
    const int cc = threadIdx.x & 7;
    const int rg = threadIdx.x >> 3;
    const int c0 = cc * 16;
    const int row0 = blockIdx.x * 128 + rg * 4;
    const float* wt = WT + cc * CSTRIDE;

    const float* p[4];
    #pragma unroll
    for (int r = 0; r < 4; ++r) {
        int rr = row0 + r; if (rr > n - 1) rr = n - 1;
        p[r] = in + (size_t)rr * H;
    }
    float acc[4][16];
    #pragma unroll
    for (int r = 0; r < 4; ++r)
        #pragma unroll
        for (int j = 0; j < 16; ++j) acc[r][j] = 0.f;
    for (int k4 = 0; k4 < H / 4; ++k4) {
        float4 a[4];
        #pragma unroll
        for (int r = 0; r < 4; ++r) a[r] = *(const float4*)(p[r] + k4 * 4);
        #pragma unroll
        for (int kk = 0; kk < 4; ++kk) {
            const float* wb = wt + (k4 * 4 + kk) * 16;
            float w[16];
            *(float4*)(w + 0)  = *(const float4*)(wb + 0);
            *(float4*)(w + 4)  = *(const float4*)(wb + 4);
            *(float4*)(w + 8)  = *(const float4*)(wb + 8);
            *(float4*)(w + 12) = *(const float4*)(wb + 12);
            float av[4];
            #pragma unroll
            for (int r = 0; r < 4; ++r) av[r] = ((const float*)&a[r])[kk];
            #pragma unroll
            for (int r = 0; r < 4; ++r)
                #pragma unroll
                for (int j = 0; j < 16; ++j)
                    acc[r][j] = fmaf(av[r], w[j], acc[r][j]);
        }
    }
    #pragma unroll
    for (int r = 0; r < 4; ++r) {
        int row = row0 + r;
        if (row < n) {
            float* orow = out + (size_t)row * H + c0;
            #pragma unroll
            for (int j4 = 0; j4 < 4; ++j4) {
                float4 o;
                o.x = fmaxf(acc[r][j4 * 4 + 0] + bias[c0 + j4 * 4 + 0], 0.f);
                o.y = fmaxf(acc[r][j4 * 4 + 1] + bias[c0 + j4 * 4 + 1], 0.f);
                o.z = fmaxf(acc[r][j4 * 4 + 2] + bias[c0 + j4 * 4 + 2], 0.f);
                o.w = fmaxf(acc[r][j4 * 4 + 3] + bias[c0 + j4 * 4 + 3], 0.f);
                *(float4*)(orow + j4 * 4) = o;
            }
        }
    }
}

__global__ __launch_bounds__(128) void pool_k(const float* __restrict__ h, const int* __restrict__ batch,
                                              float* __restrict__ P, int n, int G) {
    int g = blockIdx.x, f = threadIdx.x;
    int lo = 0, hi = n;
    while (lo < hi) { int m = (lo + hi) >> 1; if (batch[m] < g) lo = m + 1; else hi = m; }
    int s0 = lo;
    hi = n;
    while (lo < hi) { int m = (lo + hi) >> 1; if (batch[m] < g + 1) lo = m + 1; else hi = m; }
    int s1 = lo;
    float a0 = 0.f, a1 = 0.f, a2 = 0.f, a3 = 0.f;
    int i = s0;
    for (; i + 4 <= s1; i += 4) {
        a0 += h[(size_t)i * H + f];
        a1 += h[(size_t)(i + 1) * H + f];
        a2 += h[(size_t)(i + 2) * H + f];
        a3 += h[(size_t)(i + 3) * H + f];
    }
    for (; i < s1; ++i) a0 += h[(size_t)i * H + f];
    float sum = (a0 + a1) + (a2 + a3);
    float c = (float)(s1 - s0); if (c < 1.f) c = 1.f;
    P[(size_t)g * H + f] = sum / c;
}

__global__ __launch_bounds__(256) void head_k(const float* __restrict__ P,
                                              const float* __restrict__ Wl1, const float* __restrict__ bl1,
                                              const float* __restrict__ Wl2, const float* __restrict__ bl2,
                                              const float* __restrict__ Wl3, const float* __restrict__ bl3,
                                              float* __restrict__ out, int G) {
    __shared__ float Wb[H * H];
    __shared__ float Tl[H * 133];
    __shared__ float w3l[H];
    int tid = threadIdx.x;
    int g0 = blockIdx.x * 128;

    if (tid < 128) w3l[tid] = Wl3[tid];
    for (int i = tid; i < H * H / 4; i += 256) ((float4*)Wb)[i] = ((const float4*)Wl1)[i];
    __syncthreads();

    const int cc = tid & 7, rg = tid >> 3, c0 = cc * 16;
    float acc[4][16];

    #pragma unroll
    for (int r = 0; r < 4; ++r)
        #pragma unroll
        for (int j = 0; j < 16; ++j) acc[r][j] = 0.f;
    const float4* P4 = (const float4*)P;
    for (int k4 = 0; k4 < H / 4; ++k4) {
        float4 a[4];
        #pragma unroll
        for (int r = 0; r < 4; ++r) a[r] = P4[(size_t)(g0 + rg * 4 + r) * 32 + k4];
        const float* wbase = Wb + (k4 * 4) * H + c0;
        #pragma unroll
        for (int kk = 0; kk < 4; ++kk) {
            float w[16];
            *(float4*)(w + 0)  = *(const float4*)(wbase + kk * H + 0);
            *(float4*)(w + 4)  = *(const float4*)(wbase + kk * H + 4);
            *(float4*)(w + 8)  = *(const float4*)(wbase + kk * H + 8);
            *(float4*)(w + 12) = *(const float4*)(wbase + kk * H + 12);
            float av[4];
            #pragma unroll
            for (int r = 0; r < 4; ++r) av[r] = ((const float*)&a[r])[kk];
            #pragma unroll
            for (int r = 0; r < 4; ++r)
                #pragma unroll
                for (int j = 0; j < 16; ++j)
                    acc[r][j] = fmaf(av[r], w[j], acc[r][j]);
        }
    }
    #pragma unroll
    for (int r = 0; r < 4; ++r) {
        int rl = rg * 4 + r;
        #pragma unroll
        for (int j = 0; j < 16; ++j)
            Tl[rl * 133 + c0 + j] = fmaxf(acc[r][j] + bl1[c0 + j], 0.f);
    }
    __syncthreads();
    for (int i = tid; i < H * H / 4; i += 256) ((float4*)Wb)[i] = ((const float4*)Wl2)[i];
    __syncthreads();

    #pragma unroll
    for (int r = 0; r < 4; ++r)
        #pragma unroll
        for (int j = 0; j < 16; ++j) acc[r][j] = 0.f;
    for (int k4 = 0; k4 < H / 4; ++k4) {
        float4 a[4];
        #pragma unroll
        for (int r = 0; r < 4; ++r) a[r] = *(const float4*)(Tl + (rg * 4 + r) * 133 + k4 * 4);
        const float* wbase = Wb + (k4 * 4) * H + c0;
        #pragma unroll
        for (int kk = 0; kk < 4; ++kk) {
            float w[16];
            *(float4*)(w + 0)  = *(const float4*)(wbase + kk * H + 0);
            *(float4*)(w + 4)  = *(const float4*)(wbase + kk * H + 4);
            *(float4*)(w + 8)  = *(const float4*)(wbase + kk * H + 8);
            *(float4*)(w + 12) = *(const float4*)(wbase + kk * H + 12);
            float av[4];
            #pragma unroll
            for (int r = 0; r < 4; ++r) av[r] = ((const float*)&a[r])[kk];
            #pragma unroll
            for (int r = 0; r < 4; ++r)
                #pragma unroll
                for (int j = 0; j < 16; ++j)
                    acc[r][j] = fmaf(av[r], w[j], acc[r][j]);
        }
    }
    float part[4];
    #pragma unroll
    for (int r = 0; r < 4; ++r) {
        float s = 0.f;
        #pragma unroll
        for (int j = 0; j < 16; ++j)
            s += fmaxf(acc[r][j] + bl2[c0 + j], 0.f) * w3l[c0 + j];
        part[r] = s;
    }
    #pragma unroll
    for (int off = 1; off < 8; off <<= 1)
        #pragma unroll
        for (int r = 0; r < 4; ++r) part[r] += __shfl_xor(part[r], off);
    if (cc == 0) {
        float bb = bl3[0];
        #pragma unroll
        for (int r = 0; r < 4; ++r) out[g0 + rg * 4 + r] = part[r] + bb;
    }
}

// ===================================================================================
// launch
// ===================================================================================

extern "C" void kernel_launch(void* const* d_in, const int* in_sizes, int n_in,
                              void* d_out, int out_size, void* d_ws, size_t ws_size,
                              hipStream_t stream) {
    const float* x     = (const float*)d_in[0];
    const int*   ei    = (const int*)d_in[1];
    const int*   batch = (const int*)d_in[2];
    const float* W1  = (const float*)d_in[3];  const float* b1  = (const float*)d_in[4];
    const float* W2  = (const float*)d_in[5];  const float* b2  = (const float*)d_in[6];
    const float* W3  = (const float*)d_in[7];  const float* b3  = (const float*)d_in[8];
    const float* Wl1 = (const float*)d_in[9];  const float* bl1 = (const float*)d_in[10];
    const float* Wl2 = (const float*)d_in[11]; const float* bl2 = (const float*)d_in[12];
    const float* Wl3 = (const float*)d_in[13]; const float* bl3 = (const float*)d_in[14];

    int N = in_sizes[0];
    int E = in_sizes[1] / 2;
    int G = out_size;
    const int* srcp = ei;
    const int* dstp = ei + E;
    int NB = (N + BN - 1) / BN;
    int nChunks = (E + CHUNK - 1) / CHUNK;
    int nTiles = (N + 127) / 128;

    char* w = (char*)d_ws;
    size_t off = 0;
    auto alloc = [&](size_t bytes) -> void* {
        void* p = w + off;
        off += (bytes + 255) & ~(size_t)255;
        return p;
    };
    int*    gcur = (int*)alloc((size_t)MAXNB * 4);
    int*    offs = (int*)alloc((size_t)N * 4);
    int*    eend = (int*)alloc((size_t)N * 4);
    int*    csr  = (int*)alloc((size_t)NB * CAP * 4);
    float*  dinv = (float*)alloc((size_t)N * 4);
    float*  sbuf = (float*)alloc((size_t)N * 4);
    float2* td   = (float2*)alloc((size_t)N * 8);
    float*  A    = (float*)alloc((size_t)N * H * 4);   // U2 -> U3 -> g1
    float*  B    = (float*)alloc((size_t)N * H * 4);   // pairbuf -> Z2 -> h3
    float*  P    = (float*)alloc((size_t)G * H * 4);   // pooled means
    float*  outp = (float*)d_out;
    unsigned* pairbuf = (unsigned*)B;
    (void)ws_size; (void)n_in;

    // ---- try cooperative mega-kernel with runtime-sized grid ----
    bool coopOk = false;
    int coopAttr = 0, cus = 0, bpc = 0;
    if (hipDeviceGetAttribute(&coopAttr, hipDeviceAttributeCooperativeLaunch, 0) == hipSuccess &&
        coopAttr != 0 &&
        hipDeviceGetAttribute(&cus, hipDeviceAttributeMultiprocessorCount, 0) == hipSuccess &&
        hipOccupancyMaxActiveBlocksPerMultiprocessor(&bpc, (const void*)mega_k, 256, 0) == hipSuccess &&
        bpc > 0 && cus > 0) {
        int gridB = bpc * cus;
        if (gridB > 4096) gridB = 4096;
        if (gridB >= 128) {
            void* kargs[] = {
                (void*)&x, (void*)&srcp, (void*)&dstp, (void*)&batch,
                (void*)&W1, (void*)&b1, (void*)&W2, (void*)&b2, (void*)&W3, (void*)&b3,
                (void*)&Wl1, (void*)&bl1, (void*)&Wl2, (void*)&bl2, (void*)&Wl3, (void*)&bl3,
                (void*)&gcur, (void*)&offs, (void*)&eend, (void*)&csr,
                (void*)&dinv, (void*)&sbuf, (void*)&td,
                (void*)&A, (void*)&B, (void*)&P, (void*)&outp,
                (void*)&N, (void*)&E, (void*)&G, (void*)&NB, (void*)&nChunks, (void*)&nTiles
            };
            hipError_t err = hipLaunchCooperativeKernel((const void*)mega_k, dim3(gridB), dim3(256),
                                                        kargs, 0, stream);
            coopOk = (err == hipSuccess);
            if (!coopOk) (void)hipGetLastError();   // clear
        }
    }

    if (!coopOk) {
        // ---- fallback: R10 multi-kernel pipeline (known-good) ----
        hipMemsetAsync(gcur, 0, (size_t)MAXNB * 4, stream);
        scatter_pairs_k<<<nChunks, 256, 0, stream>>>(srcp, dstp, gcur, pairbuf, E, NB);
        build_csr_k<<<NB, 512, 0, stream>>>(pairbuf, gcur, x, offs, eend, dinv, sbuf, csr, N);
        agg1_k<<<(N + 255) / 256, 256, 0, stream>>>(sbuf, offs, eend, csr, dinv, td, N);
        l2_agg_k<<<(N + 3) / 4, 256, 0, stream>>>(td, offs, eend, csr, W1, b1, A, N);
        gemm_post_k<<<nTiles, 256, 0, stream>>>(A, W2, b2, dinv, B, N);
        agg3_k<<<(N + 3) / 4, 256, 0, stream>>>(B, offs, eend, csr, dinv, A, N);
        gemm_k<<<nTiles, 256, 0, stream>>>(A, W3, b3, B, N);
        pool_k<<<G, 128, 0, stream>>>(B, batch, P, N, G);
        head_k<<<(G + 127) / 128, 256, 0, stream>>>(P, Wl1, bl1, Wl2, bl2, Wl3, bl3, outp, G);
    }
}

// Round 13
// 506.435 us; speedup vs baseline: 3.9838x; 3.9838x over previous
//
#include <hip/hip_runtime.h>

#define H 128
#define SHIFT 9             // nodes per coarse bucket = 512
#define BN 512
#define MAXNB 256           // max coarse buckets (N <= 131072)
#define CHUNK 4096          // edges per scatter block
#define CAP 16384           // slack capacity per bucket (exp 8192, sigma ~90)
#define CSTRIDE (H * 16 + 4)   // 2052 floats: per-cc transposed W block, conflict-free

// ============ graph build: slack-bucket counting sort (no global histogram pass) ============
// Packing: src < 2^17, local node < 512 -> record = (local<<17)|src fits u32.
// Bucket b owns pairbuf/csr region [b*CAP, (b+1)*CAP); gcur[b] (memset 0) allocates within.

__global__ __launch_bounds__(256) void scatter_pairs_k(const int* __restrict__ src,
                                                       const int* __restrict__ dst,
                                                       int* __restrict__ gcur,
                                                       unsigned* __restrict__ pairbuf,
                                                       int E, int NBv) {
    __shared__ unsigned stage[CHUNK];
    __shared__ unsigned char stb[CHUNK];
    __shared__ int hist[MAXNB], basel[MAXNB], cur[MAXNB], gbase[MAXNB];
    __shared__ int total;
    int tid = threadIdx.x;
    int base = blockIdx.x * CHUNK;

    int mysrc[16], mydst[16];
    #pragma unroll
    for (int i = 0; i < 16; ++i) {
        int e = base + i * 256 + tid;
        if (e < E) { mysrc[i] = src[e]; mydst[i] = dst[e]; } else mydst[i] = -1;
    }
    hist[tid] = 0;
    __syncthreads();
    #pragma unroll
    for (int i = 0; i < 16; ++i)
        if (mydst[i] >= 0) atomicAdd(&hist[mydst[i] >> SHIFT], 1);
    __syncthreads();
    if (tid == 0) {
        int run = 0;
        for (int b = 0; b < NBv; ++b) { basel[b] = run; run += hist[b]; }
        total = run;
    }
    __syncthreads();
    if (tid < NBv) {
        cur[tid] = basel[tid];
        if (hist[tid] > 0) gbase[tid] = tid * CAP + atomicAdd(&gcur[tid], hist[tid]);
    }
    __syncthreads();
    #pragma unroll
    for (int i = 0; i < 16; ++i)
        if (mydst[i] >= 0) {
            int b = mydst[i] >> SHIFT;
            int slot = atomicAdd(&cur[b], 1);
            stage[slot] = ((unsigned)(mydst[i] & (BN - 1)) << 17) | (unsigned)mysrc[i];
            stb[slot] = (unsigned char)b;
        }
    __syncthreads();
    for (int s = tid; s < total; s += 256) {
        int b = stb[s];
        pairbuf[gbase[b] + (s - basel[b])] = stage[s];   // contiguous runs -> full-line writes
    }
}

// one block per bucket: LDS hist + scan -> offs/eend/dinv/s, then in-bucket scatter (L2-local)
__global__ __launch_bounds__(512) void build_csr_k(const unsigned* __restrict__ pairbuf,
                                                   const int* __restrict__ gcur,
                                                   const float* __restrict__ x,
                                                   int* __restrict__ offs, int* __restrict__ eend,
                                                   float* __restrict__ dinv, float* __restrict__ s,
                                                   int* __restrict__ csr, int N) {
    __shared__ int hist[BN];
    __shared__ int cur[BN];
    __shared__ int ps[BN];
    int b = blockIdx.x, tid = threadIdx.x;
    int node0 = b << SHIFT;
    int e0 = b * CAP, e1 = e0 + gcur[b];
    hist[tid] = 0;
    __syncthreads();
    for (int p = e0 + tid; p < e1; p += 512)
        atomicAdd(&hist[pairbuf[p] >> 17], 1);
    __syncthreads();
    int v0 = hist[tid];
    ps[tid] = v0;
    __syncthreads();
    for (int off = 1; off < BN; off <<= 1) {
        int t = (tid >= off) ? ps[tid - off] : 0;
        __syncthreads();
        ps[tid] += t;
        __syncthreads();
    }
    int g0 = e0 + ps[tid] - v0;
    int n0 = node0 + tid;
    if (n0 < N) {
        float d = rsqrtf((float)(v0 + 1));
        offs[n0] = g0;
        eend[n0] = g0 + v0;
        dinv[n0] = d;
        s[n0] = x[n0] * d;      // fused s_k
    }
    cur[tid] = g0;
    __syncthreads();
    for (int p = e0 + tid; p < e1; p += 512) {
        unsigned v = pairbuf[p];
        int pos = atomicAdd(&cur[v >> 17], 1);
        csr[pos] = (int)(v & 0x1FFFFu);
    }
}

// ---------------- layer 1: t_i = dinv_i*(s_i + sum s_src); emits (t, dinv) pairs ----------------

__global__ void agg1_k(const float* __restrict__ s, const int* __restrict__ offs,
                       const int* __restrict__ eend, const int* __restrict__ csr,
                       const float* __restrict__ dinv, float2* __restrict__ td, int n) {
    int i = blockIdx.x * blockDim.x + threadIdx.x;
    if (i >= n) return;
    float sum = s[i];
    int e0 = offs[i], e1 = eend[i];
    float a0 = 0.f, a1 = 0.f, a2 = 0.f, a3 = 0.f;
    int p = e0;
    for (; p + 4 <= e1; p += 4) {
        a0 += s[csr[p]]; a1 += s[csr[p + 1]]; a2 += s[csr[p + 2]]; a3 += s[csr[p + 3]];
    }
    for (; p < e1; ++p) sum += s[csr[p]];
    sum += (a0 + a1) + (a2 + a3);
    float d = dinv[i];
    td[i] = make_float2(sum * d, d);
}

// ------- layer-2 fused aggregation over SCALARS (aggregate-then-GEMM algebra) -------
// U2_i = dinv_i * sum_{j in N(i)+self} dinv_j * relu(t_j*w1 + b1)

__global__ __launch_bounds__(256) void l2_agg_k(const float2* __restrict__ td,
                                                const int* __restrict__ offs,
                                                const int* __restrict__ eend,
                                                const int* __restrict__ csr,
                                                const float* __restrict__ w1,
                                                const float* __restrict__ b1,
                                                float* __restrict__ U, int n) {
    int node = blockIdx.x * 4 + (threadIdx.x >> 6);
    int lane = threadIdx.x & 63;
    if (node >= n) return;
    float wa = w1[lane],      wb = w1[lane + 64];
    float ba = b1[lane],      bb = b1[lane + 64];
    float2 self = td[node];
    float sa = fmaxf(fmaf(self.x, wa, ba), 0.f) * self.y;
    float sb = fmaxf(fmaf(self.x, wb, bb), 0.f) * self.y;
    int e0 = offs[node], e1 = eend[node];
    int p = e0;
    for (; p + 8 <= e1; p += 8) {
        float2 v[8];
        #pragma unroll
        for (int u = 0; u < 8; ++u) v[u] = td[csr[p + u]];
        #pragma unroll
        for (int u = 0; u < 8; ++u) {
            sa = fmaf(fmaxf(fmaf(v[u].x, wa, ba), 0.f), v[u].y, sa);
            sb = fmaf(fmaxf(fmaf(v[u].x, wb, bb), 0.f), v[u].y, sb);
        }
    }
    for (; p < e1; ++p) {
        float2 v = td[csr[p]];
        sa = fmaf(fmaxf(fmaf(v.x, wa, ba), 0.f), v.y, sa);
        sb = fmaf(fmaxf(fmaf(v.x, wb, bb), 0.f), v.y, sb);
    }
    float d = self.y;
    U[(size_t)node * H + lane]      = sa * d;
    U[(size_t)node * H + lane + 64] = sb * d;
}

// ---- conflict-free W staging: WT[cc][k][j], stride CSTRIDE per cc ----

__device__ __forceinline__ void stage_WT(const float* __restrict__ W, float* __restrict__ WT) {
    for (int idx = threadIdx.x; idx < H * H / 4; idx += 256) {
        float4 v = ((const float4*)W)[idx];
        int k  = idx >> 5;
        int c4 = idx & 31;
        int cc = c4 >> 2;
        int j  = (c4 & 3) * 4;
        *(float4*)(WT + cc * CSTRIDE + k * 16 + j) = v;
    }
}

// ------- GEMM with post-activation row scale: Z2 = pscale[row] * relu(in@W + bias) -------

__global__ __launch_bounds__(256) void gemm_post_k(const float* __restrict__ in, const float* __restrict__ W,
                                                   const float* __restrict__ bias, const float* __restrict__ pscale,
                                                   float* __restrict__ out, int n) {
    __shared__ float WT[8 * CSTRIDE];
    stage_WT(W, WT);
    __syncthreads();
    const int cc = threadIdx.x & 7;
    const int rg = threadIdx.x >> 3;
    const int c0 = cc * 16;
    const int row0 = blockIdx.x * 128 + rg * 4;
    const float* wt = WT + cc * CSTRIDE;

    const float* p[4];
    #pragma unroll
    for (int r = 0; r < 4; ++r) {
        int rr = row0 + r; if (rr > n - 1) rr = n - 1;
        p[r] = in + (size_t)rr * H;
    }

    float acc[4][16];
    #pragma unroll
    for (int r = 0; r < 4; ++r)
        #pragma unroll
        for (int j = 0; j < 16; ++j) acc[r][j] = 0.f;

    for (int k4 = 0; k4 < H / 4; ++k4) {
        float4 a[4];
        #pragma unroll
        for (int r = 0; r < 4; ++r) a[r] = *(const float4*)(p[r] + k4 * 4);
        #pragma unroll
        for (int kk = 0; kk < 4; ++kk) {
            const float* wb = wt + (k4 * 4 + kk) * 16;
            float w[16];
            *(float4*)(w + 0)  = *(const float4*)(wb + 0);
            *(float4*)(w + 4)  = *(const float4*)(wb + 4);
            *(float4*)(w + 8)  = *(const float4*)(wb + 8);
            *(float4*)(w + 12) = *(const float4*)(wb + 12);
            float av[4];
            #pragma unroll
            for (int r = 0; r < 4; ++r) av[r] = ((const float*)&a[r])[kk];
            #pragma unroll
            for (int r = 0; r < 4; ++r)
                #pragma unroll
                for (int j = 0; j < 16; ++j)
                    acc[r][j] = fmaf(av[r], w[j], acc[r][j]);
        }
    }

    #pragma unroll
    for (int r = 0; r < 4; ++r) {
        int row = row0 + r;
        if (row < n) {
            float sc = pscale[row];
            float* orow = out + (size_t)row * H + c0;
            #pragma unroll
            for (int j4 = 0; j4 < 4; ++j4) {
                float4 o;
                o.x = fmaxf(acc[r][j4 * 4 + 0] + bias[c0 + j4 * 4 + 0], 0.f) * sc;
                o.y = fmaxf(acc[r][j4 * 4 + 1] + bias[c0 + j4 * 4 + 1], 0.f) * sc;
                o.z = fmaxf(acc[r][j4 * 4 + 2] + bias[c0 + j4 * 4 + 2], 0.f) * sc;
                o.w = fmaxf(acc[r][j4 * 4 + 3] + bias[c0 + j4 * 4 + 3], 0.f) * sc;
                *(float4*)(orow + j4 * 4) = o;
            }
        }
    }
}

// ------- whole-wave gather of one node's neighbor-row sum -------

__device__ __forceinline__ float4 gather_row_sum(const float4* __restrict__ hs4,
                                                 const int* __restrict__ csr,
                                                 int node, int e0, int e1, int half, int l) {
    float4 acc[8];
    #pragma unroll
    for (int u = 0; u < 8; ++u) acc[u] = make_float4(0.f, 0.f, 0.f, 0.f);
    if (half == 0) acc[0] = hs4[(size_t)node * 32 + l];   // self loop
    int q = e0;
    for (; q + 15 < e1; q += 16) {
        int idx[8];
        #pragma unroll
        for (int u = 0; u < 8; ++u) idx[u] = csr[q + 2 * u + half];
        #pragma unroll
        for (int u = 0; u < 8; ++u) {
            float4 v = hs4[(size_t)idx[u] * 32 + l];
            acc[u].x += v.x; acc[u].y += v.y; acc[u].z += v.z; acc[u].w += v.w;
        }
    }
    for (; q + 7 < e1; q += 8) {
        int idx[4];
        #pragma unroll
        for (int u = 0; u < 4; ++u) idx[u] = csr[q + 2 * u + half];
        #pragma unroll
        for (int u = 0; u < 4; ++u) {
            float4 v = hs4[(size_t)idx[u] * 32 + l];
            acc[u].x += v.x; acc[u].y += v.y; acc[u].z += v.z; acc[u].w += v.w;
        }
    }
    for (; q < e1; q += 2) {
        int off = q + half;
        if (off < e1) {
            float4 v = hs4[(size_t)csr[off] * 32 + l];
            acc[0].x += v.x; acc[0].y += v.y; acc[0].z += v.z; acc[0].w += v.w;
        }
    }
    float4 sum;
    sum.x = ((acc[0].x + acc[1].x) + (acc[2].x + acc[3].x)) + ((acc[4].x + acc[5].x) + (acc[6].x + acc[7].x));
    sum.y = ((acc[0].y + acc[1].y) + (acc[2].y + acc[3].y)) + ((acc[4].y + acc[5].y) + (acc[6].y + acc[7].y));
    sum.z = ((acc[0].z + acc[1].z) + (acc[2].z + acc[3].z)) + ((acc[4].z + acc[5].z) + (acc[6].z + acc[7].z));
    sum.w = ((acc[0].w + acc[1].w) + (acc[2].w + acc[3].w)) + ((acc[4].w + acc[5].w) + (acc[6].w + acc[7].w));
    sum.x += __shfl_xor(sum.x, 32);
    sum.y += __shfl_xor(sum.y, 32);
    sum.z += __shfl_xor(sum.z, 32);
    sum.w += __shfl_xor(sum.w, 32);
    return sum;
}

// ------- layer-3 aggregation of Z2 rows: U3_i = dinv_i * (Z2_i + sum Z2_src) -------

__global__ __launch_bounds__(256) void agg3_k(const float* __restrict__ Z, const int* __restrict__ offs,
                                              const int* __restrict__ eend, const int* __restrict__ csr,
                                              const float* __restrict__ dinv,
                                              float* __restrict__ U, int n) {
    int node = blockIdx.x * 4 + (threadIdx.x >> 6);
    int lane = threadIdx.x & 63;
    int half = lane >> 5;
    int l = lane & 31;
    if (node >= n) return;
    const float4* Z4 = (const float4*)Z;
    float4 sum = gather_row_sum(Z4, csr, node, offs[node], eend[node], half, l);
    if (half == 0) {
        float d = dinv[node];
        float4 o;
        o.x = sum.x * d; o.y = sum.y * d; o.z = sum.z * d; o.w = sum.w * d;
        ((float4*)U)[(size_t)node * 32 + l] = o;
    }
}

// ------- layer-3 GEMM: h3 = relu(U3@W3 + b3) -------

__global__ __launch_bounds__(256) void gemm_k(const float* __restrict__ in, const float* __restrict__ W,
                                              const float* __restrict__ bias,
                                              float* __restrict__ out, int n) {
    __shared__ float WT[8 * CSTRIDE];
    stage_WT(W, WT);
    __syncthreads();
    const int cc = threadIdx.x & 7;
    const int rg = threadIdx.x >> 3;
    const int c0 = cc * 16;
    const int row0 = blockIdx.x * 128 + rg * 4;
    const float* wt = WT + cc * CSTRIDE;

    const float* p[4];
    #pragma unroll
    for (int r = 0; r < 4; ++r) {
        int rr = row0 + r; if (rr > n - 1) rr = n - 1;
        p[r] = in + (size_t)rr * H;
    }

    float acc[4][16];
    #pragma unroll
    for (int r = 0; r < 4; ++r)
        #pragma unroll
        for (int j = 0; j < 16; ++j) acc[r][j] = 0.f;

    for (int k4 = 0; k4 < H / 4; ++k4) {
        float4 a[4];
        #pragma unroll
        for (int r = 0; r < 4; ++r) a[r] = *(const float4*)(p[r] + k4 * 4);
        #pragma unroll
        for (int kk = 0; kk < 4; ++kk) {
            const float* wb = wt + (k4 * 4 + kk) * 16;
            float w[16];
            *(float4*)(w + 0)  = *(const float4*)(wb + 0);
            *(float4*)(w + 4)  = *(const float4*)(wb + 4);
            *(float4*)(w + 8)  = *(const float4*)(wb + 8);
            *(float4*)(w + 12) = *(const float4*)(wb + 12);
            float av[4];
            #pragma unroll
            for (int r = 0; r < 4; ++r) av[r] = ((const float*)&a[r])[kk];
            #pragma unroll
            for (int r = 0; r < 4; ++r)
                #pragma unroll
                for (int j = 0; j < 16; ++j)
                    acc[r][j] = fmaf(av[r], w[j], acc[r][j]);
        }
    }

    #pragma unroll
    for (int r = 0; r < 4; ++r) {
        int row = row0 + r;
        if (row < n) {
            float* orow = out + (size_t)row * H + c0;
            #pragma unroll
            for (int j4 = 0; j4 < 4; ++j4) {
                float4 o;
                o.x = fmaxf(acc[r][j4 * 4 + 0] + bias[c0 + j4 * 4 + 0], 0.f);
                o.y = fmaxf(acc[r][j4 * 4 + 1] + bias[c0 + j4 * 4 + 1], 0.f);
                o.z = fmaxf(acc[r][j4 * 4 + 2] + bias[c0 + j4 * 4 + 2], 0.f);
                o.w = fmaxf(acc[r][j4 * 4 + 3] + bias[c0 + j4 * 4 + 3], 0.f);
                *(float4*)(orow + j4 * 4) = o;
            }
        }
    }
}

// ---------------- pooling (binary search over sorted batch ids; overwrite, no atomics) --------

__global__ __launch_bounds__(128) void pool_k(const float* __restrict__ h, const int* __restrict__ batch,
                                              float* __restrict__ P, int n, int G) {
    int g = blockIdx.x, f = threadIdx.x;
    int lo = 0, hi = n;
    while (lo < hi) { int m = (lo + hi) >> 1; if (batch[m] < g) lo = m + 1; else hi = m; }
    int s0 = lo;
    hi = n;
    while (lo < hi) { int m = (lo + hi) >> 1; if (batch[m] < g + 1) lo = m + 1; else hi = m; }
    int s1 = lo;
    float a0 = 0.f, a1 = 0.f, a2 = 0.f, a3 = 0.f;
    int i = s0;
    for (; i + 4 <= s1; i += 4) {
        a0 += h[(size_t)i * H + f];
        a1 += h[(size_t)(i + 1) * H + f];
        a2 += h[(size_t)(i + 2) * H + f];
        a3 += h[(size_t)(i + 3) * H + f];
    }
    for (; i < s1; ++i) a0 += h[(size_t)i * H + f];
    float sum = (a0 + a1) + (a2 + a3);
    float c = (float)(s1 - s0); if (c < 1.f) c = 1.f;
    P[(size_t)g * H + f] = sum / c;
}

// ------- fused MLP head: relu(@Wl1+bl1) + relu(@Wl2+bl2) + dot Wl3 + bl3 -------

__global__ __launch_bounds__(256) void head_k(const float* __restrict__ P,
                                              const float* __restrict__ Wl1, const float* __restrict__ bl1,
                                              const float* __restrict__ Wl2, const float* __restrict__ bl2,
                                              const float* __restrict__ Wl3, const float* __restrict__ bl3,
                                              float* __restrict__ out, int G) {
    __shared__ float Wb[H * H];
    __shared__ float Tl[H * 133];
    __shared__ float w3l[H];
    int tid = threadIdx.x;
    int g0 = blockIdx.x * 128;

    if (tid < 128) w3l[tid] = Wl3[tid];
    for (int i = tid; i < H * H / 4; i += 256) ((float4*)Wb)[i] = ((const float4*)Wl1)[i];
    __syncthreads();

    const int cc = tid & 7, rg = tid >> 3, c0 = cc * 16;
    float acc[4][16];

    #pragma unroll
    for (int r = 0; r < 4; ++r)
        #pragma unroll
        for (int j = 0; j < 16; ++j) acc[r][j] = 0.f;
    const float4* P4 = (const float4*)P;
    for (int k4 = 0; k4 < H / 4; ++k4) {
        float4 a[4];
        #pragma unroll
        for (int r = 0; r < 4; ++r) a[r] = P4[(size_t)(g0 + rg * 4 + r) * 32 + k4];
        const float* wbase = Wb + (k4 * 4) * H + c0;
        #pragma unroll
        for (int kk = 0; kk < 4; ++kk) {
            float w[16];
            *(float4*)(w + 0)  = *(const float4*)(wbase + kk * H + 0);
            *(float4*)(w + 4)  = *(const float4*)(wbase + kk * H + 4);
            *(float4*)(w + 8)  = *(const float4*)(wbase + kk * H + 8);
            *(float4*)(w + 12) = *(const float4*)(wbase + kk * H + 12);
            float av[4];
            #pragma unroll
            for (int r = 0; r < 4; ++r) av[r] = ((const float*)&a[r])[kk];
            #pragma unroll
            for (int r = 0; r < 4; ++r)
                #pragma unroll
                for (int j = 0; j < 16; ++j)
                    acc[r][j] = fmaf(av[r], w[j], acc[r][j]);
        }
    }
    #pragma unroll
    for (int r = 0; r < 4; ++r) {
        int rl = rg * 4 + r;
        #pragma unroll
        for (int j = 0; j < 16; ++j)
            Tl[rl * 133 + c0 + j] = fmaxf(acc[r][j] + bl1[c0 + j], 0.f);
    }
    __syncthreads();
    for (int i = tid; i < H * H / 4; i += 256) ((float4*)Wb)[i] = ((const float4*)Wl2)[i];
    __syncthreads();

    #pragma unroll
    for (int r = 0; r < 4; ++r)
        #pragma unroll
        for (int j = 0; j < 16; ++j) acc[r][j] = 0.f;
    for (int k4 = 0; k4 < H / 4; ++k4) {
        float4 a[4];
        #pragma unroll
        for (int r = 0; r < 4; ++r) a[r] = *(const float4*)(Tl + (rg * 4 + r) * 133 + k4 * 4);
        const float* wbase = Wb + (k4 * 4) * H + c0;
        #pragma unroll
        for (int kk = 0; kk < 4; ++kk) {
            float w[16];
            *(float4*)(w + 0)  = *(const float4*)(wbase + kk * H + 0);
            *(float4*)(w + 4)  = *(const float4*)(wbase + kk * H + 4);
            *(float4*)(w + 8)  = *(const float4*)(wbase + kk * H + 8);
            *(float4*)(w + 12) = *(const float4*)(wbase + kk * H + 12);
            float av[4];
            #pragma unroll
            for (int r = 0; r < 4; ++r) av[r] = ((const float*)&a[r])[kk];
            #pragma unroll
            for (int r = 0; r < 4; ++r)
                #pragma unroll
                for (int j = 0; j < 16; ++j)
                    acc[r][j] = fmaf(av[r], w[j], acc[r][j]);
        }
    }
    float part[4];
    #pragma unroll
    for (int r = 0; r < 4; ++r) {
        float s = 0.f;
        #pragma unroll
        for (int j = 0; j < 16; ++j)
            s += fmaxf(acc[r][j] + bl2[c0 + j], 0.f) * w3l[c0 + j];
        part[r] = s;
    }
    #pragma unroll
    for (int off = 1; off < 8; off <<= 1)
        #pragma unroll
        for (int r = 0; r < 4; ++r) part[r] += __shfl_xor(part[r], off);
    if (cc == 0) {
        float bb = bl3[0];
        #pragma unroll
        for (int r = 0; r < 4; ++r) out[g0 + rg * 4 + r] = part[r] + bb;
    }
}

// ---------------- launch ----------------

extern "C" void kernel_launch(void* const* d_in, const int* in_sizes, int n_in,
                              void* d_out, int out_size, void* d_ws, size_t ws_size,
                              hipStream_t stream) {
    const float* x     = (const float*)d_in[0];
    const int*   ei    = (const int*)d_in[1];
    const int*   batch = (const int*)d_in[2];
    const float* W1  = (const float*)d_in[3];  const float* b1  = (const float*)d_in[4];
    const float* W2  = (const float*)d_in[5];  const float* b2  = (const float*)d_in[6];
    const float* W3  = (const float*)d_in[7];  const float* b3  = (const float*)d_in[8];
    const float* Wl1 = (const float*)d_in[9];  const float* bl1 = (const float*)d_in[10];
    const float* Wl2 = (const float*)d_in[11]; const float* bl2 = (const float*)d_in[12];
    const float* Wl3 = (const float*)d_in[13]; const float* bl3 = (const float*)d_in[14];

    const int N = in_sizes[0];
    const int E = in_sizes[1] / 2;
    const int G = out_size;
    const int* srcp = ei;
    const int* dstp = ei + E;
    const int NB = (N + BN - 1) / BN;    // 196 for N=100000

    char* w = (char*)d_ws;
    size_t off = 0;
    auto alloc = [&](size_t bytes) -> void* {
        void* p = w + off;
        off += (bytes + 255) & ~(size_t)255;
        return p;
    };
    int*    gcur   = (int*)alloc((size_t)MAXNB * 4);
    int*    offs   = (int*)alloc((size_t)N * 4);
    int*    eend   = (int*)alloc((size_t)N * 4);
    int*    csr    = (int*)alloc((size_t)NB * CAP * 4);   // bucket-padded
    float*  dinv   = (float*)alloc((size_t)N * 4);
    float*  sbuf   = (float*)alloc((size_t)N * 4);
    float2* td     = (float2*)alloc((size_t)N * 8);
    float*  A      = (float*)alloc((size_t)N * H * 4);   // U2, then U3
    float*  B      = (float*)alloc((size_t)N * H * 4);   // pairbuf, then Z2, then h3
    float*  P      = (float*)alloc((size_t)G * H * 4);   // pooled means
    unsigned* pairbuf = (unsigned*)B;   // alias (NB*CAP*4 = 12.9 MB << N*H*4)
    (void)ws_size; (void)n_in;

    // --- graph build (slack buckets: no histogram pass) ---
    hipMemsetAsync(gcur, 0, (size_t)MAXNB * 4, stream);
    scatter_pairs_k<<<(E + CHUNK - 1) / CHUNK, 256, 0, stream>>>(srcp, dstp, gcur, pairbuf, E, NB);
    build_csr_k<<<NB, 512, 0, stream>>>(pairbuf, gcur, x, offs, eend, dinv, sbuf, csr, N);

    // --- layer 1 (scalar feature) ---
    agg1_k<<<(N + 255) / 256, 256, 0, stream>>>(sbuf, offs, eend, csr, dinv, td, N);

    // --- layer 2: scalar-gather fused aggregation, then GEMM ---
    l2_agg_k<<<(N + 3) / 4, 256, 0, stream>>>(td, offs, eend, csr, W1, b1, A, N);
    gemm_post_k<<<(N + 127) / 128, 256, 0, stream>>>(A, W2, b2, dinv, B, N);   // B = Z2

    // --- layer 3: row-gather aggregation, GEMM, pool ---
    agg3_k<<<(N + 3) / 4, 256, 0, stream>>>(B, offs, eend, csr, dinv, A, N);   // A = U3
    gemm_k<<<(N + 127) / 128, 256, 0, stream>>>(A, W3, b3, B, N);              // B = h3
    pool_k<<<G, 128, 0, stream>>>(B, batch, P, N, G);

    // --- fused MLP head ---
    head_k<<<(G + 127) / 128, 256, 0, stream>>>(P, Wl1, bl1, Wl2, bl2, Wl3, bl3,
                                                (float*)d_out, G);
}